// Round 5
// baseline (290.513 us; speedup 1.0000x reference)
//
#include <hip/hip_runtime.h>
#include <hip/hip_bf16.h>
#include <math.h>

typedef float f32x4 __attribute__((ext_vector_type(4)));
typedef short s16x8 __attribute__((ext_vector_type(8)));
typedef unsigned short us16x4 __attribute__((ext_vector_type(4)));
typedef unsigned short us16x8 __attribute__((ext_vector_type(8)));
typedef unsigned int u32x2 __attribute__((ext_vector_type(2)));

#define MFMA16(a, b, c) __builtin_amdgcn_mfma_f32_16x16x32_bf16(a, b, c, 0, 0, 0)

static constexpr int B_ = 2, S_ = 2048, D_ = 1024, H_ = 16, HD_ = 64;
// Q pre-scale: HD^-0.5 * log2(e)  -> flash softmax in exp2 domain, no max needed
static constexpr float QSCALE = 0.125f * 1.44269504088896340736f;

__device__ __forceinline__ unsigned short f2bf(float f) {
    unsigned int u = __builtin_bit_cast(unsigned int, f);
    u += 0x7fffu + ((u >> 16) & 1);  // round-to-nearest-even
    return (unsigned short)(u >> 16);
}

// packed fp32x2 -> bf16x2 (lo=a, hi=b), RNE. HW inst on gfx950.
#if defined(__has_builtin) && __has_builtin(__builtin_amdgcn_cvt_pk_bf16_f32)
typedef __bf16 bf16x2v __attribute__((ext_vector_type(2)));
__device__ __forceinline__ unsigned int pk_bf16(float a, float b) {
    return __builtin_bit_cast(unsigned int, __builtin_amdgcn_cvt_pk_bf16_f32(a, b));
}
#else
__device__ __forceinline__ unsigned int pk_bf16(float a, float b) {
    return ((unsigned int)f2bf(a)) | (((unsigned int)f2bf(b)) << 16);
}
#endif

__device__ __forceinline__ void glds16(const unsigned short* g, unsigned short* l) {
    __builtin_amdgcn_global_load_lds(
        (const __attribute__((address_space(1))) void*)g,
        (__attribute__((address_space(3))) void*)l, 16, 0, 0);
}

__device__ __forceinline__ void glds16f(const float* g, float* l) {
    __builtin_amdgcn_global_load_lds(
        (const __attribute__((address_space(1))) void*)g,
        (__attribute__((address_space(3))) void*)l, 16, 0, 0);
}

// ---------------------------------------------------------------------------
// Weight transpose: Wt[(h*64+e)*1024 + d] = W[h*65536 + d*64 + e]
// ---------------------------------------------------------------------------
__global__ __launch_bounds__(256) void transpose_w3(const float* __restrict__ W0,
                                                    const float* __restrict__ W1,
                                                    const float* __restrict__ W2,
                                                    unsigned short* __restrict__ Wt3) {
    const int z = blockIdx.z;
    const float* W = (z == 0) ? W0 : (z == 1) ? W1 : W2;
    unsigned short* dst = Wt3 + ((size_t)z << 20);
    const int h = blockIdx.x >> 2, dg = blockIdx.x & 3;
    const int lane = threadIdx.x & 63, w = threadIdx.x >> 6;
    const float* Wh = W + ((size_t)h << 16);
#pragma unroll
    for (int it = 0; it < 8; it++) {
        int d0 = dg * 256 + it * 32 + w * 8;
        us16x8 o;
#pragma unroll
        for (int j = 0; j < 8; j++) o[j] = f2bf(Wh[(d0 + j) * 64 + lane]);
        *(us16x8*)&dst[(size_t)(h * 64 + lane) * 1024 + d0] = o;
    }
}

// ---------------------------------------------------------------------------
// QKV projection GEMM, A staged directly from f32 inputs.
// A-tile: [128 rows][64 k] f32 in LDS (32 KB), 16-granule/row XOR swizzle;
// bf16 fragments built in-register via cvt_pk (RNE).
// B-tile: bf16 weights (transpose_w3 output), 8-granule swizzle.
// z=0 Q -> row-major [B,S,D] (pre-scaled), z=1 K -> row-major,
// z=2 V -> transposed [B,H,HD,S]. XCD-chunked bijective swizzle (T1).
// ---------------------------------------------------------------------------
__global__ __launch_bounds__(256) void gemm_qkv(const float* __restrict__ Qf,
                                                const float* __restrict__ Kf,
                                                const float* __restrict__ Vf,
                                                const unsigned short* __restrict__ Wt3,
                                                const float* __restrict__ bq,
                                                const float* __restrict__ bk,
                                                const float* __restrict__ bv,
                                                unsigned short* __restrict__ Qr,
                                                unsigned short* __restrict__ Kr,
                                                unsigned short* __restrict__ Vt) {
    __shared__ float Asf[128 * 64];           // 32 KB (f32 A tile)
    __shared__ unsigned short Bs[128 * 64];   // 16 KB (bf16 B tile)
    // flat hw id (x fastest) -> XCD-chunked work id
    const int flat = blockIdx.x + (blockIdx.y << 3) + (blockIdx.z << 8);  // 0..767
    const int wid = (flat & 7) * 96 + (flat >> 3);                        // bijective (768%8==0)
    const int z = wid >> 8;
    const int by = (wid & 255) >> 3;
    const int bx = wid & 7;
    const float* A = (z == 0) ? Qf : (z == 1) ? Kf : Vf;
    const float* bias = (z == 0) ? bq : (z == 1) ? bk : bv;
    const int m0 = by * 128, n0 = bx * 128;

    const int tid = threadIdx.x;
    const int lane = tid & 63;
    const int w = tid >> 6, wm = w & 1, wn = w >> 1;
    const int l16 = lane & 15, quad = lane >> 4;
    // A staging: 16 rows/round, granule su = (tid&15) ^ (row&15)
    const int arow = tid >> 4;
    const int su = (tid & 15) ^ arow;
    const float* Ag = A + (size_t)(m0 + arow) * 1024 + su * 4;
    float* Alf = Asf + tid * 4;
    // B staging: 32 rows/round
    const int srow = tid >> 3;
    const int sg = (tid & 7) ^ (srow & 7);
    const unsigned short* Bg = Wt3 + ((size_t)z << 20) + (size_t)(n0 + srow) * 1024 + sg * 8;
    unsigned short* Bl = Bs + tid * 8;
    const int xo8 = l16 & 7;

    f32x4 acc[4][4] = {};
    for (int k0 = 0; k0 < 1024; k0 += 64) {
        __syncthreads();
#pragma unroll
        for (int c = 0; c < 8; c++)
            glds16f(Ag + (size_t)c * 16 * 1024 + k0, Alf + c * 1024);
#pragma unroll
        for (int c = 0; c < 4; c++)
            glds16(Bg + (size_t)c * 32 * 1024 + k0, Bl + c * 2048);
        __syncthreads();
#pragma unroll
        for (int kc = 0; kc < 2; kc++) {
            s16x8 bf[4];
#pragma unroll
            for (int nt = 0; nt < 4; nt++)
                bf[nt] = *(const s16x8*)&Bs[(wn * 64 + nt * 16 + l16) * 64 +
                                            (((kc * 4 + quad) ^ xo8) * 8)];
#pragma unroll
            for (int mt = 0; mt < 4; mt++) {
                const int row = wm * 64 + mt * 16 + l16;
                const int u = kc * 8 + quad * 2;
                const int e = row & 15;
                f32x4 lo = *(const f32x4*)&Asf[row * 64 + ((u ^ e) * 4)];
                f32x4 hi = *(const f32x4*)&Asf[row * 64 + (((u + 1) ^ e) * 4)];
                s16x8 af;
                ((unsigned int*)&af)[0] = pk_bf16(lo[0], lo[1]);
                ((unsigned int*)&af)[1] = pk_bf16(lo[2], lo[3]);
                ((unsigned int*)&af)[2] = pk_bf16(hi[0], hi[1]);
                ((unsigned int*)&af)[3] = pk_bf16(hi[2], hi[3]);
#pragma unroll
                for (int nt = 0; nt < 4; nt++)
                    acc[mt][nt] = MFMA16(af, bf[nt], acc[mt][nt]);
            }
        }
    }

    const float scl = (z == 0) ? QSCALE : 1.0f;

    __syncthreads();  // all waves done with K-loop LDS reads
    unsigned short* T = ((unsigned short*)Asf) + w * 4096;  // per-wave 64x64 in Asf
#pragma unroll
    for (int mt = 0; mt < 4; mt++)
#pragma unroll
        for (int nt = 0; nt < 4; nt++) {
            int nl = nt * 16 + l16;
            float bsv = bias[n0 + wn * 64 + nl];
#pragma unroll
            for (int r = 0; r < 4; r++) {
                int ml = mt * 16 + quad * 4 + r;
                unsigned short val = f2bf((acc[mt][nt][r] + bsv) * scl);
                int row = (z == 2) ? nl : ml;
                int col = (z == 2) ? ml : nl;
                T[row * 64 + (((col >> 3) ^ (row & 7)) * 8) + (col & 7)] = val;
            }
        }
    // same-wave RAW: compiler orders via lgkmcnt; per-wave private region
#pragma unroll
    for (int it = 0; it < 8; it++) {
        int rr = it * 8 + (lane >> 3);
        int g = lane & 7;
        us16x8 vv = *(const us16x8*)&T[rr * 64 + ((g ^ (rr & 7)) * 8)];
        if (z == 2) {
            int n = n0 + wn * 64 + rr;           // h*64+e
            int mb = m0 + wm * 64 + g * 8;
            int b = mb >> 11, s = mb & 2047;
            *(us16x8*)&Vt[(((size_t)(b * H_ + (n >> 6))) * HD_ + (n & 63)) * S_ + s] = vv;
        } else {
            unsigned short* dst = z ? Kr : Qr;
            *(us16x8*)&dst[(size_t)(m0 + wm * 64 + rr) * 1024 + n0 + wn * 64 + g * 8] = vv;
        }
    }
}

// ---------------------------------------------------------------------------
// Final: C_f32[4096][1024] = Cc * Wp^T + bp.  128x64 tile -> 512 blocks
// (2 blocks/CU). B (Wp) staged directly from f32, 16-granule XOR scheme.
// XCD-chunked swizzle.
// ---------------------------------------------------------------------------
__global__ __launch_bounds__(256) void gemm_out(const unsigned short* __restrict__ A,
                                                const float* __restrict__ Wp,
                                                const float* __restrict__ bias,
                                                float* __restrict__ C) {
    __shared__ unsigned short As[128 * 64];   // 16 KB (bf16 A tile)
    __shared__ float Bsf[64 * 64];            // 16 KB (f32 B tile)
    const int tid = threadIdx.x;
    const int lane = tid & 63;
    const int w = tid >> 6, wm = w & 1, wn = w >> 1;  // wn 0..1
    const int l16 = lane & 15, quad = lane >> 4;
    const int flat = blockIdx.x + (blockIdx.y << 4);  // 0..511
    const int wid = (flat & 7) * 64 + (flat >> 3);    // bijective (512%8==0)
    const int m0 = (wid >> 4) * 128, n0 = (wid & 15) * 64;
    const int srow = tid >> 3;
    const int sg = (tid & 7) ^ (srow & 7);
    const unsigned short* Ag = A + (size_t)(m0 + srow) * 1024 + sg * 8;
    unsigned short* Al = As + tid * 8;
    // B staging: 16 rows/round, f32 granules
    const int brow = tid >> 4;
    const int su = (tid & 15) ^ brow;
    const float* Bg = Wp + (size_t)(n0 + brow) * 1024 + su * 4;
    float* Blf = Bsf + tid * 4;
    const int xo8 = l16 & 7;

    f32x4 acc[4][2] = {};
    for (int k0 = 0; k0 < 1024; k0 += 64) {
        __syncthreads();
#pragma unroll
        for (int c = 0; c < 4; c++)
            glds16(Ag + (size_t)c * 32 * 1024 + k0, Al + c * 2048);
#pragma unroll
        for (int c = 0; c < 4; c++)
            glds16f(Bg + (size_t)c * 16 * 1024 + k0, Blf + c * 1024);
        __syncthreads();
#pragma unroll
        for (int kc = 0; kc < 2; kc++) {
            s16x8 bf[2];
#pragma unroll
            for (int nt = 0; nt < 2; nt++) {
                const int row = wn * 32 + nt * 16 + l16;
                const int u = kc * 8 + quad * 2;
                const int e = row & 15;
                f32x4 lo = *(const f32x4*)&Bsf[row * 64 + ((u ^ e) * 4)];
                f32x4 hi = *(const f32x4*)&Bsf[row * 64 + (((u + 1) ^ e) * 4)];
                ((unsigned int*)&bf[nt])[0] = pk_bf16(lo[0], lo[1]);
                ((unsigned int*)&bf[nt])[1] = pk_bf16(lo[2], lo[3]);
                ((unsigned int*)&bf[nt])[2] = pk_bf16(hi[0], hi[1]);
                ((unsigned int*)&bf[nt])[3] = pk_bf16(hi[2], hi[3]);
            }
#pragma unroll
            for (int mt = 0; mt < 4; mt++) {
                s16x8 af = *(const s16x8*)&As[(wm * 64 + mt * 16 + l16) * 64 +
                                              (((kc * 4 + quad) ^ xo8) * 8)];
#pragma unroll
                for (int nt = 0; nt < 2; nt++)
                    acc[mt][nt] = MFMA16(af, bf[nt], acc[mt][nt]);
            }
        }
    }
    const int lq = quad;
#pragma unroll
    for (int mt = 0; mt < 4; mt++)
#pragma unroll
        for (int nt = 0; nt < 2; nt++)
#pragma unroll
            for (int r = 0; r < 4; r++) {
                int mg = m0 + wm * 64 + mt * 16 + lq * 4 + r;
                int ng = n0 + wn * 32 + nt * 16 + l16;
                C[(size_t)mg * 1024 + ng] = acc[mt][nt][r] + bias[ng];
            }
}

// ---------------------------------------------------------------------------
// Flash attention v8: TLP-scaled. QBLK=32, 2 waves / 128 threads per block,
// grid 2048 blocks -> 7 blocks/CU (LDS 20.5 KB: K single-buffered 8K +
// V 8K + P 4.5K). More independent barrier-groups per CU (7 vs 4) overlap
// the per-iter dep chain (ds_read -> QK MFMA -> exp2 -> P round-trip -> PV).
// Counted vmcnt: stage K then V; vmcnt(4)+barrier (K ready, V in flight,
// V latency hides under QK+softmax); vmcnt(0)+barrier before PV.
// Q,K row-major [B,S,D] bf16 (Q pre-scaled); V: [B,H,HD,S].
// grid: x = bh (head -> XCD pinned via bh%8), y = q-block (32 rows).
// ---------------------------------------------------------------------------
__global__ __launch_bounds__(128) void flash_attn(const unsigned short* __restrict__ Qr,
                                                  const unsigned short* __restrict__ Kr,
                                                  const unsigned short* __restrict__ Vt,
                                                  unsigned short* __restrict__ Cc) {
    __shared__ unsigned short Ks[64 * 64];       // [key][d], 8 KB
    __shared__ unsigned short Vs[64 * 64];       // [e][s-rel], 8 KB
    constexpr int LDT = 72;
    __shared__ unsigned short P2[2][16 * LDT];   // per-wave P^T: [q][key], 4.5 KB

    const int tid = threadIdx.x;
    const int lane = tid & 63, w = tid >> 6;     // w in {0,1}
    const int l16 = lane & 15, quad = lane >> 4;
    const int bh = blockIdx.x, q0 = blockIdx.y * 32;
    const int b = bh >> 4, h = bh & 15;
    const int s_q = q0 + w * 16 + l16;           // this lane's q-row

    const unsigned short* Qp = Qr + ((size_t)(b * S_ + s_q)) * D_ + h * HD_;
    s16x8 aq0 = *(const s16x8*)&Qp[quad * 8];
    s16x8 aq1 = *(const s16x8*)&Qp[32 + quad * 8];

    const int srow = tid >> 3;                   // 0..15
    const int sg = (tid & 7) ^ (srow & 7);
    const unsigned short* kg = Kr + ((size_t)(b * S_ + srow)) * D_ + h * HD_ + sg * 8;
    const unsigned short* vg = Vt + (((size_t)(b * H_ + h)) * HD_ + srow) * S_ + sg * 8;
    unsigned short* Kl = Ks + tid * 8;
    unsigned short* Vl = Vs + tid * 8;
    unsigned short* Pw = P2[w];
    const int pbase = l16 * LDT + quad * 4;      // P store base (per-lane)
    const int xo = l16 & 7;

    float l_part = 0.f;
    f32x4 o[4] = {};
    const f32x4 z4 = {0.f, 0.f, 0.f, 0.f};

    for (int t = 0; t < 32; ++t) {
        // stage-overwrite protection: all waves' LDS reads of tile t-1 retired
        // (each wave's reads were lgkm-waited before its MFMAs, which precede this)
        asm volatile("s_barrier" ::: "memory");
        // stage K(t) then V(t): 16 rows per round, 4 rounds each
#pragma unroll
        for (int c = 0; c < 4; c++)
            glds16(kg + (size_t)(c * 16) * D_, Kl + c * 1024);
#pragma unroll
        for (int c = 0; c < 4; c++)
            glds16(vg + (size_t)(c * 16) * S_, Vl + c * 1024);
        kg += (size_t)64 * D_;
        vg += 64;
        // K landed everywhere; the 4 V glds stay in flight (counted vmcnt)
        asm volatile("s_waitcnt vmcnt(4)\n\ts_barrier" ::: "memory");

        // scores^T: D[key][q] = K·Q^T ; keys g*16+quad*4+r, col q=l16
        __builtin_amdgcn_s_setprio(1);
#pragma unroll
        for (int g = 0; g < 4; g++) {
            int row = g * 16 + l16;
            s16x8 kb0 = *(const s16x8*)&Ks[row * 64 + ((quad ^ xo) * 8)];
            s16x8 kb1 = *(const s16x8*)&Ks[row * 64 + (((4 + quad) ^ xo) * 8)];
            f32x4 sc = MFMA16(kb0, aq0, z4);
            sc = MFMA16(kb1, aq1, sc);
            float e0 = exp2f(sc[0]), e1 = exp2f(sc[1]);
            float e2 = exp2f(sc[2]), e3 = exp2f(sc[3]);
            l_part += (e0 + e1) + (e2 + e3);
            u32x2 pv;
            pv[0] = pk_bf16(e0, e1);
            pv[1] = pk_bf16(e2, e3);
            *(u32x2*)&Pw[pbase + g * 16] = pv;   // 4 contig keys, 8B store
        }
        __builtin_amdgcn_s_setprio(0);
        // P as B-operand for PV: B[k=key][n=q] = Pw[q=l16][key] (same-wave, DS in-order)
        s16x8 pB0 = *(const s16x8*)&Pw[l16 * LDT + quad * 8];
        s16x8 pB1 = *(const s16x8*)&Pw[l16 * LDT + 32 + quad * 8];

        // V(t) landed everywhere
        asm volatile("s_waitcnt vmcnt(0)\n\ts_barrier" ::: "memory");

        // o^T[e][q] += V^T · P^T
        __builtin_amdgcn_s_setprio(1);
#pragma unroll
        for (int tt = 0; tt < 4; tt++) {
            int row = tt * 16 + l16;
            s16x8 v0 = *(const s16x8*)&Vs[row * 64 + ((quad ^ xo) * 8)];
            s16x8 v1 = *(const s16x8*)&Vs[row * 64 + (((4 + quad) ^ xo) * 8)];
            o[tt] = MFMA16(v0, pB0, o[tt]);
            o[tt] = MFMA16(v1, pB1, o[tt]);
        }
        __builtin_amdgcn_s_setprio(0);
    }

    float l = l_part;
    l += __shfl_xor(l, 16);
    l += __shfl_xor(l, 32);
    float rinv = 1.0f / l;
    unsigned short* Cp = Cc + ((size_t)(b * S_ + s_q)) * D_ + h * HD_;
#pragma unroll
    for (int t = 0; t < 4; t++) {
        u32x2 ov;
        ov[0] = pk_bf16(o[t][0] * rinv, o[t][1] * rinv);
        ov[1] = pk_bf16(o[t][2] * rinv, o[t][3] * rinv);
        *(u32x2*)&Cp[t * 16 + quad * 4] = ov;
    }
}

// ---------------------------------------------------------------------------
extern "C" void kernel_launch(void* const* d_in, const int* in_sizes, int n_in,
                              void* d_out, int out_size, void* d_ws, size_t ws_size,
                              hipStream_t stream) {
    const float* K_in = (const float*)d_in[0];
    const float* V_in = (const float*)d_in[1];
    const float* Q_in = (const float*)d_in[2];
    const float* Wk   = (const float*)d_in[3];
    const float* bk   = (const float*)d_in[4];
    const float* Wq   = (const float*)d_in[5];
    const float* bq   = (const float*)d_in[6];
    const float* Wv   = (const float*)d_in[7];
    const float* bv   = (const float*)d_in[8];
    const float* Wp   = (const float*)d_in[9];
    const float* bp   = (const float*)d_in[10];

    unsigned short* ws16 = (unsigned short*)d_ws;
    const size_t MC = 1u << 20;
    unsigned short* Wt3 = ws16;            // 3M bf16 transposed QKV weights
    unsigned short* Qr  = Wt3 + 3 * MC;    // 4M [B,S,D] projected, pre-scaled
    unsigned short* Kr  = Qr + 4 * MC;     // 4M [B,S,D]
    unsigned short* Vt  = Kr + 4 * MC;     // 4M [B,H,HD,S]
    unsigned short* Cc  = Vt + 4 * MC;     // 4M [B,S,D] attention output

    transpose_w3<<<dim3(64, 1, 3), 256, 0, stream>>>(Wq, Wk, Wv, Wt3);

    gemm_qkv<<<dim3(8, 32, 3), 256, 0, stream>>>(Q_in, K_in, V_in, Wt3, bq, bk, bv,
                                                 Qr, Kr, Vt);

    flash_attn<<<dim3(32, 64), 128, 0, stream>>>(Qr, Kr, Vt, Cc);

    gemm_out<<<dim3(16, 32), 256, 0, stream>>>(Cc, Wp, bp, (float*)d_out);
}

// Round 6
// 281.962 us; speedup vs baseline: 1.0303x; 1.0303x over previous
//
#include <hip/hip_runtime.h>
#include <hip/hip_bf16.h>
#include <math.h>

typedef float f32x4 __attribute__((ext_vector_type(4)));
typedef short s16x8 __attribute__((ext_vector_type(8)));
typedef unsigned short us16x4 __attribute__((ext_vector_type(4)));
typedef unsigned short us16x8 __attribute__((ext_vector_type(8)));
typedef unsigned int u32x2 __attribute__((ext_vector_type(2)));

#define MFMA16(a, b, c) __builtin_amdgcn_mfma_f32_16x16x32_bf16(a, b, c, 0, 0, 0)

static constexpr int B_ = 2, S_ = 2048, D_ = 1024, H_ = 16, HD_ = 64;
// Q pre-scale: HD^-0.5 * log2(e)  -> flash softmax in exp2 domain, no max needed
static constexpr float QSCALE = 0.125f * 1.44269504088896340736f;

__device__ __forceinline__ unsigned short f2bf(float f) {
    unsigned int u = __builtin_bit_cast(unsigned int, f);
    u += 0x7fffu + ((u >> 16) & 1);  // round-to-nearest-even
    return (unsigned short)(u >> 16);
}

// packed fp32x2 -> bf16x2 (lo=a, hi=b), RNE. HW inst on gfx950.
#if defined(__has_builtin) && __has_builtin(__builtin_amdgcn_cvt_pk_bf16_f32)
typedef __bf16 bf16x2v __attribute__((ext_vector_type(2)));
__device__ __forceinline__ unsigned int pk_bf16(float a, float b) {
    return __builtin_bit_cast(unsigned int, __builtin_amdgcn_cvt_pk_bf16_f32(a, b));
}
#else
__device__ __forceinline__ unsigned int pk_bf16(float a, float b) {
    return ((unsigned int)f2bf(a)) | (((unsigned int)f2bf(b)) << 16);
}
#endif

__device__ __forceinline__ void glds16(const unsigned short* g, unsigned short* l) {
    __builtin_amdgcn_global_load_lds(
        (const __attribute__((address_space(1))) void*)g,
        (__attribute__((address_space(3))) void*)l, 16, 0, 0);
}

// cvt 8 f32 (2 x f32x4) -> 8 bf16 packed
__device__ __forceinline__ us16x8 cvt8(const f32x4 lo, const f32x4 hi) {
    us16x8 o;
    ((unsigned int*)&o)[0] = pk_bf16(lo[0], lo[1]);
    ((unsigned int*)&o)[1] = pk_bf16(lo[2], lo[3]);
    ((unsigned int*)&o)[2] = pk_bf16(hi[0], hi[1]);
    ((unsigned int*)&o)[3] = pk_bf16(hi[2], hi[3]);
    return o;
}

// ---------------------------------------------------------------------------
// Weight transpose: Wt[(h*64+e)*1024 + d] = W[h*65536 + d*64 + e]
// ---------------------------------------------------------------------------
__global__ __launch_bounds__(256) void transpose_w3(const float* __restrict__ W0,
                                                    const float* __restrict__ W1,
                                                    const float* __restrict__ W2,
                                                    unsigned short* __restrict__ Wt3) {
    const int z = blockIdx.z;
    const float* W = (z == 0) ? W0 : (z == 1) ? W1 : W2;
    unsigned short* dst = Wt3 + ((size_t)z << 20);
    const int h = blockIdx.x >> 2, dg = blockIdx.x & 3;
    const int lane = threadIdx.x & 63, w = threadIdx.x >> 6;
    const float* Wh = W + ((size_t)h << 16);
#pragma unroll
    for (int it = 0; it < 8; it++) {
        int d0 = dg * 256 + it * 32 + w * 8;
        us16x8 o;
#pragma unroll
        for (int j = 0; j < 8; j++) o[j] = f2bf(Wh[(d0 + j) * 64 + lane]);
        *(us16x8*)&dst[(size_t)(h * 64 + lane) * 1024 + d0] = o;
    }
}

// ---------------------------------------------------------------------------
// QKV projection GEMM v3: issue-early / drain-late pipeline (T14+T3-min).
//  Double-buffered LDS tiles (A,B bf16, 64 KB total -> 2 blocks/CU).
//  Per K-step: issue A(t+1) f32 loads to regs + B(t+1) glds into buf^1
//  BEFORE computing tile t; after compute, cvt A(t+1)->bf16, ds_write, then
//  __syncthreads (drains B(t+1) whose latency was hidden under compute).
//  Compiler auto-emits counted waitcnts for the reg loads (m97 evidence).
//  Inner compute loop == verified R3 bf16 core. Epilogue unchanged.
// z=0 Q -> row-major [B,S,D] (pre-scaled), z=1 K -> row-major,
// z=2 V -> transposed [B,H,HD,S]. XCD-chunked bijective swizzle (T1).
// ---------------------------------------------------------------------------
__global__ __launch_bounds__(256) void gemm_qkv(const float* __restrict__ Qf,
                                                const float* __restrict__ Kf,
                                                const float* __restrict__ Vf,
                                                const unsigned short* __restrict__ Wt3,
                                                const float* __restrict__ bq,
                                                const float* __restrict__ bk,
                                                const float* __restrict__ bv,
                                                unsigned short* __restrict__ Qr,
                                                unsigned short* __restrict__ Kr,
                                                unsigned short* __restrict__ Vt) {
    __shared__ unsigned short As[2][128 * 64];   // 2 x 16 KB
    __shared__ unsigned short Bs[2][128 * 64];   // 2 x 16 KB
    // flat hw id (x fastest) -> XCD-chunked work id
    const int flat = blockIdx.x + (blockIdx.y << 3) + (blockIdx.z << 8);  // 0..767
    const int wid = (flat & 7) * 96 + (flat >> 3);                        // bijective
    const int z = wid >> 8;
    const int by = (wid & 255) >> 3;
    const int bx = wid & 7;
    const float* A = (z == 0) ? Qf : (z == 1) ? Kf : Vf;
    const float* bias = (z == 0) ? bq : (z == 1) ? bk : bv;
    const int m0 = by * 128, n0 = bx * 128;

    const int tid = threadIdx.x;
    const int lane = tid & 63;
    const int w = tid >> 6, wm = w & 1, wn = w >> 1;
    const int l16 = lane & 15, quad = lane >> 4;
    const int srow = tid >> 3;                    // 0..31
    const int sg = (tid & 7) ^ (srow & 7);        // XOR-swizzled k-granule
    const float* Ag = A + (size_t)(m0 + srow) * 1024 + sg * 8;
    const unsigned short* Bg = Wt3 + ((size_t)z << 20) + (size_t)(n0 + srow) * 1024 + sg * 8;
    const int xo = l16 & 7;

    f32x4 ar[4][2];
    f32x4 acc[4][4] = {};

    // ---- prologue: stage tile 0 ----
#pragma unroll
    for (int c = 0; c < 4; c++) {
        ar[c][0] = *(const f32x4*)(Ag + (size_t)c * 32 * 1024);
        ar[c][1] = *(const f32x4*)(Ag + (size_t)c * 32 * 1024 + 4);
        glds16(Bg + (size_t)c * 32 * 1024, &Bs[0][tid * 8 + c * 2048]);
    }
#pragma unroll
    for (int c = 0; c < 4; c++)
        *(us16x8*)&As[0][tid * 8 + c * 2048] = cvt8(ar[c][0], ar[c][1]);
    __syncthreads();

    for (int t = 0; t < 16; ++t) {
        const int cur = t & 1, nxt = cur ^ 1;
        const int k0n = (t + 1) * 64;
        if (t < 15) {
            // issue next-tile loads BEFORE compute (latency hides under MFMA)
#pragma unroll
            for (int c = 0; c < 4; c++) {
                ar[c][0] = *(const f32x4*)(Ag + (size_t)c * 32 * 1024 + k0n);
                ar[c][1] = *(const f32x4*)(Ag + (size_t)c * 32 * 1024 + k0n + 4);
            }
#pragma unroll
            for (int c = 0; c < 4; c++)
                glds16(Bg + (size_t)c * 32 * 1024 + k0n, &Bs[nxt][tid * 8 + c * 2048]);
        }
        // compute tile t (verified bf16 core)
#pragma unroll
        for (int kc = 0; kc < 2; kc++) {
            s16x8 bf[4];
#pragma unroll
            for (int nt = 0; nt < 4; nt++)
                bf[nt] = *(const s16x8*)&Bs[cur][(wn * 64 + nt * 16 + l16) * 64 +
                                                 (((kc * 4 + quad) ^ xo) * 8)];
#pragma unroll
            for (int mt = 0; mt < 4; mt++) {
                s16x8 af = *(const s16x8*)&As[cur][(wm * 64 + mt * 16 + l16) * 64 +
                                                   (((kc * 4 + quad) ^ xo) * 8)];
#pragma unroll
                for (int nt = 0; nt < 4; nt++)
                    acc[mt][nt] = MFMA16(af, bf[nt], acc[mt][nt]);
            }
        }
        if (t < 15) {
            // write-late: cvt + publish A(t+1) (compiler waits only the reg loads)
#pragma unroll
            for (int c = 0; c < 4; c++)
                *(us16x8*)&As[nxt][tid * 8 + c * 2048] = cvt8(ar[c][0], ar[c][1]);
        }
        __syncthreads();   // drains B(t+1) glds (hidden under compute) + orders ds_writes
    }

    const float scl = (z == 0) ? QSCALE : 1.0f;

    __syncthreads();  // all waves done with K-loop LDS reads
    unsigned short* T = ((unsigned short*)As) + w * 4096;  // per-wave 64x64 scratch (32 KB)
#pragma unroll
    for (int mt = 0; mt < 4; mt++)
#pragma unroll
        for (int nt = 0; nt < 4; nt++) {
            int nl = nt * 16 + l16;
            float bsv = bias[n0 + wn * 64 + nl];
#pragma unroll
            for (int r = 0; r < 4; r++) {
                int ml = mt * 16 + quad * 4 + r;
                unsigned short val = f2bf((acc[mt][nt][r] + bsv) * scl);
                int row = (z == 2) ? nl : ml;
                int col = (z == 2) ? ml : nl;
                T[row * 64 + (((col >> 3) ^ (row & 7)) * 8) + (col & 7)] = val;
            }
        }
    // same-wave RAW: compiler orders via lgkmcnt; per-wave private region
#pragma unroll
    for (int it = 0; it < 8; it++) {
        int rr = it * 8 + (lane >> 3);
        int g = lane & 7;
        us16x8 vv = *(const us16x8*)&T[rr * 64 + ((g ^ (rr & 7)) * 8)];
        if (z == 2) {
            int n = n0 + wn * 64 + rr;           // h*64+e
            int mb = m0 + wm * 64 + g * 8;
            int b = mb >> 11, s = mb & 2047;
            *(us16x8*)&Vt[(((size_t)(b * H_ + (n >> 6))) * HD_ + (n & 63)) * S_ + s] = vv;
        } else {
            unsigned short* dst = z ? Kr : Qr;
            *(us16x8*)&dst[(size_t)(m0 + wm * 64 + rr) * 1024 + n0 + wn * 64 + g * 8] = vv;
        }
    }
}

// ---------------------------------------------------------------------------
// Final GEMM v3: C_f32[4096][1024] = Cc * Wp^T + bp.  128x64 tile, 512 blocks
// (2 blocks/CU). Same issue-early/drain-late pipeline: A (Cc bf16) via glds
// double-buffered; B (Wp f32) reg-staged -> cvt -> ds_write (write-late).
// LDS 48 KB. XCD-chunked swizzle.
// ---------------------------------------------------------------------------
__global__ __launch_bounds__(256) void gemm_out(const unsigned short* __restrict__ A,
                                                const float* __restrict__ Wp,
                                                const float* __restrict__ bias,
                                                float* __restrict__ C) {
    __shared__ unsigned short As[2][128 * 64];   // 2 x 16 KB
    __shared__ unsigned short Bs[2][64 * 64];    // 2 x 8 KB
    const int tid = threadIdx.x;
    const int lane = tid & 63;
    const int w = tid >> 6, wm = w & 1, wn = w >> 1;  // wn 0..1
    const int l16 = lane & 15, quad = lane >> 4;
    const int flat = blockIdx.x + (blockIdx.y << 4);  // 0..511
    const int wid = (flat & 7) * 64 + (flat >> 3);    // bijective (512%8==0)
    const int m0 = (wid >> 4) * 128, n0 = (wid & 15) * 64;
    const int srow = tid >> 3;                    // 0..31
    const int sg = (tid & 7) ^ (srow & 7);
    const unsigned short* Ag = A + (size_t)(m0 + srow) * 1024 + sg * 8;
    const float* Bg = Wp + (size_t)(n0 + srow) * 1024 + sg * 8;
    const int xo = l16 & 7;

    f32x4 br[2][2];
    f32x4 acc[4][2] = {};

    // ---- prologue: stage tile 0 ----
#pragma unroll
    for (int c = 0; c < 2; c++) {
        br[c][0] = *(const f32x4*)(Bg + (size_t)c * 32 * 1024);
        br[c][1] = *(const f32x4*)(Bg + (size_t)c * 32 * 1024 + 4);
    }
#pragma unroll
    for (int c = 0; c < 4; c++)
        glds16(Ag + (size_t)c * 32 * 1024, &As[0][tid * 8 + c * 2048]);
#pragma unroll
    for (int c = 0; c < 2; c++)
        *(us16x8*)&Bs[0][tid * 8 + c * 2048] = cvt8(br[c][0], br[c][1]);
    __syncthreads();

    for (int t = 0; t < 16; ++t) {
        const int cur = t & 1, nxt = cur ^ 1;
        const int k0n = (t + 1) * 64;
        if (t < 15) {
#pragma unroll
            for (int c = 0; c < 2; c++) {
                br[c][0] = *(const f32x4*)(Bg + (size_t)c * 32 * 1024 + k0n);
                br[c][1] = *(const f32x4*)(Bg + (size_t)c * 32 * 1024 + k0n + 4);
            }
#pragma unroll
            for (int c = 0; c < 4; c++)
                glds16(Ag + (size_t)c * 32 * 1024 + k0n, &As[nxt][tid * 8 + c * 2048]);
        }
#pragma unroll
        for (int kc = 0; kc < 2; kc++) {
            s16x8 bf[2];
#pragma unroll
            for (int nt = 0; nt < 2; nt++)
                bf[nt] = *(const s16x8*)&Bs[cur][(wn * 32 + nt * 16 + l16) * 64 +
                                                 (((kc * 4 + quad) ^ xo) * 8)];
#pragma unroll
            for (int mt = 0; mt < 4; mt++) {
                s16x8 af = *(const s16x8*)&As[cur][(wm * 64 + mt * 16 + l16) * 64 +
                                                   (((kc * 4 + quad) ^ xo) * 8)];
#pragma unroll
                for (int nt = 0; nt < 2; nt++)
                    acc[mt][nt] = MFMA16(af, bf[nt], acc[mt][nt]);
            }
        }
        if (t < 15) {
#pragma unroll
            for (int c = 0; c < 2; c++)
                *(us16x8*)&Bs[nxt][tid * 8 + c * 2048] = cvt8(br[c][0], br[c][1]);
        }
        __syncthreads();
    }
    const int lq = quad;
#pragma unroll
    for (int mt = 0; mt < 4; mt++)
#pragma unroll
        for (int nt = 0; nt < 2; nt++)
#pragma unroll
            for (int r = 0; r < 4; r++) {
                int mg = m0 + wm * 64 + mt * 16 + lq * 4 + r;
                int ng = n0 + wn * 32 + nt * 16 + l16;
                C[(size_t)mg * 1024 + ng] = acc[mt][nt][r] + bias[ng];
            }
}

// ---------------------------------------------------------------------------
// Flash attention v6 (best measured): pipelined staging.
//  K double-buffered + 1-iter-ahead prefetch; V single-buffered with counted
//  vmcnt(2) mid-barrier (K prefetch stays in flight); s_setprio around MFMA.
// Q,K row-major [B,S,D] bf16 (Q pre-scaled); V: [B,H,HD,S].
// grid: x = bh (all q-blocks of a head land on one XCD), y = q-block.
// ---------------------------------------------------------------------------
__global__ __launch_bounds__(256) void flash_attn(const unsigned short* __restrict__ Qr,
                                                  const unsigned short* __restrict__ Kr,
                                                  const unsigned short* __restrict__ Vt,
                                                  unsigned short* __restrict__ Cc) {
    __shared__ unsigned short Ks[2][64 * 64];    // [buf][key][d], double-buffered
    __shared__ unsigned short Vs[64 * 64];       // [e][s-rel], single-buffered
    constexpr int LDT = 72;
    __shared__ unsigned short P4[4][16 * LDT];   // per-wave P^T: [q][key]

    const int tid = threadIdx.x;
    const int lane = tid & 63, w = tid >> 6;
    const int l16 = lane & 15, quad = lane >> 4;
    const int bh = blockIdx.x, q0 = blockIdx.y * 64;
    const int b = bh >> 4, h = bh & 15;
    const int s_q = q0 + w * 16 + l16;           // this lane's q-row

    const unsigned short* Qp = Qr + ((size_t)(b * S_ + s_q)) * D_ + h * HD_;

    const int srow = tid >> 3;
    const int sg = (tid & 7) ^ (srow & 7);
    const unsigned short* kg = Kr + ((size_t)(b * S_ + srow)) * D_ + h * HD_ + sg * 8;
    const unsigned short* vg = Vt + (((size_t)(b * H_ + h)) * HD_ + srow) * S_ + sg * 8;
    unsigned short* Vl = Vs + tid * 8;
    unsigned short* Pw = P4[w];
    const int pbase = l16 * LDT + quad * 4;      // P store base (per-lane)
    const int xo = l16 & 7;

    // prologue: stage K tile 0 into Ks[0]
    glds16(kg, &Ks[0][tid * 8]);
    glds16(kg + (size_t)32 * D_, &Ks[0][tid * 8 + 2048]);
    kg += (size_t)64 * D_;

    s16x8 aq0 = *(const s16x8*)&Qp[quad * 8];
    s16x8 aq1 = *(const s16x8*)&Qp[32 + quad * 8];

    float l_part = 0.f;
    f32x4 o[4] = {};
    const f32x4 z4 = {0.f, 0.f, 0.f, 0.f};

    asm volatile("s_waitcnt vmcnt(0) lgkmcnt(0)\n\ts_barrier" ::: "memory");

    int cur = 0;
    for (int t = 0; t < 32; ++t) {
        const int last = (t == 31);
        // stage V(t): Vs free (all waves finished PV(t-1) before last barrier)
        glds16(vg, Vl);
        glds16(vg + (size_t)32 * S_, Vl + 2048);
        vg += 64;
        if (!last) {
            // stage K(t+1) into the other K buffer (read slot freed at iter t-1)
            unsigned short* Kn = &Ks[cur ^ 1][tid * 8];
            glds16(kg, Kn);
            glds16(kg + (size_t)32 * D_, Kn + 2048);
            kg += (size_t)64 * D_;
        }

        // scores^T on Ks[cur]: D[key][q] = K·Q^T ; keys g*16+quad*4+r, col q=l16
        const unsigned short* Kc_ = &Ks[cur][0];
        __builtin_amdgcn_s_setprio(1);
#pragma unroll
        for (int g = 0; g < 4; g++) {
            int row = g * 16 + l16;
            s16x8 kb0 = *(const s16x8*)&Kc_[row * 64 + ((quad ^ xo) * 8)];
            s16x8 kb1 = *(const s16x8*)&Kc_[row * 64 + (((4 + quad) ^ xo) * 8)];
            f32x4 sc = MFMA16(kb0, aq0, z4);
            sc = MFMA16(kb1, aq1, sc);
            float e0 = exp2f(sc[0]), e1 = exp2f(sc[1]);
            float e2 = exp2f(sc[2]), e3 = exp2f(sc[3]);
            l_part += (e0 + e1) + (e2 + e3);
            u32x2 pv;
            pv[0] = pk_bf16(e0, e1);
            pv[1] = pk_bf16(e2, e3);
            *(u32x2*)&Pw[pbase + g * 16] = pv;   // 4 contig keys, 8B store
        }
        __builtin_amdgcn_s_setprio(0);
        // P as B-operand for PV: B[k=key][n=q] = Pw[q=l16][key] (same-wave, DS in-order)
        s16x8 pB0 = *(const s16x8*)&Pw[l16 * LDT + quad * 8];
        s16x8 pB1 = *(const s16x8*)&Pw[l16 * LDT + 32 + quad * 8];

        // mid-iter: V(t) landed (leave the 2 newer K(t+1) glds in flight), all waves sync
        if (!last)
            asm volatile("s_waitcnt vmcnt(2)\n\ts_barrier" ::: "memory");
        else
            asm volatile("s_waitcnt vmcnt(0)\n\ts_barrier" ::: "memory");

        // o^T[e][q] += V^T · P^T
        __builtin_amdgcn_s_setprio(1);
#pragma unroll
        for (int tt = 0; tt < 4; tt++) {
            int row = tt * 16 + l16;
            s16x8 v0 = *(const s16x8*)&Vs[row * 64 + ((quad ^ xo) * 8)];
            s16x8 v1 = *(const s16x8*)&Vs[row * 64 + (((4 + quad) ^ xo) * 8)];
            o[tt] = MFMA16(v0, pB0, o[tt]);
            o[tt] = MFMA16(v1, pB1, o[tt]);
        }
        __builtin_amdgcn_s_setprio(0);
        // end-of-iter: my LDS reads retired (Ks[cur]/Vs safe to overwrite next iter),
        // K(t+1) landed (had a full iteration of slack)
        asm volatile("s_waitcnt vmcnt(0) lgkmcnt(0)\n\ts_barrier" ::: "memory");
        cur ^= 1;
    }

    float l = l_part;
    l += __shfl_xor(l, 16);
    l += __shfl_xor(l, 32);
    float rinv = 1.0f / l;
    unsigned short* Cp = Cc + ((size_t)(b * S_ + s_q)) * D_ + h * HD_;
#pragma unroll
    for (int t = 0; t < 4; t++) {
        u32x2 ov;
        ov[0] = pk_bf16(o[t][0] * rinv, o[t][1] * rinv);
        ov[1] = pk_bf16(o[t][2] * rinv, o[t][3] * rinv);
        *(u32x2*)&Cp[t * 16 + quad * 4] = ov;
    }
}

// ---------------------------------------------------------------------------
extern "C" void kernel_launch(void* const* d_in, const int* in_sizes, int n_in,
                              void* d_out, int out_size, void* d_ws, size_t ws_size,
                              hipStream_t stream) {
    const float* K_in = (const float*)d_in[0];
    const float* V_in = (const float*)d_in[1];
    const float* Q_in = (const float*)d_in[2];
    const float* Wk   = (const float*)d_in[3];
    const float* bk   = (const float*)d_in[4];
    const float* Wq   = (const float*)d_in[5];
    const float* bq   = (const float*)d_in[6];
    const float* Wv   = (const float*)d_in[7];
    const float* bv   = (const float*)d_in[8];
    const float* Wp   = (const float*)d_in[9];
    const float* bp   = (const float*)d_in[10];

    unsigned short* ws16 = (unsigned short*)d_ws;
    const size_t MC = 1u << 20;
    unsigned short* Wt3 = ws16;            // 3M bf16 transposed QKV weights
    unsigned short* Qr  = Wt3 + 3 * MC;    // 4M [B,S,D] projected, pre-scaled
    unsigned short* Kr  = Qr + 4 * MC;     // 4M [B,S,D]
    unsigned short* Vt  = Kr + 4 * MC;     // 4M [B,H,HD,S]
    unsigned short* Cc  = Vt + 4 * MC;     // 4M [B,S,D] attention output

    transpose_w3<<<dim3(64, 1, 3), 256, 0, stream>>>(Wq, Wk, Wv, Wt3);

    gemm_qkv<<<dim3(8, 32, 3), 256, 0, stream>>>(Q_in, K_in, V_in, Wt3, bq, bk, bv,
                                                 Qr, Kr, Vt);

    flash_attn<<<dim3(32, 32), 256, 0, stream>>>(Qr, Kr, Vt, Cc);

    gemm_out<<<dim3(16, 32), 256, 0, stream>>>(Cc, Wp, bp, (float*)d_out);
}

// Round 7
// 251.768 us; speedup vs baseline: 1.1539x; 1.1199x over previous
//
#include <hip/hip_runtime.h>
#include <hip/hip_bf16.h>
#include <math.h>

typedef float f32x4 __attribute__((ext_vector_type(4)));
typedef short s16x8 __attribute__((ext_vector_type(8)));
typedef unsigned short us16x4 __attribute__((ext_vector_type(4)));
typedef unsigned short us16x8 __attribute__((ext_vector_type(8)));
typedef unsigned int u32x2 __attribute__((ext_vector_type(2)));

#define MFMA16(a, b, c) __builtin_amdgcn_mfma_f32_16x16x32_bf16(a, b, c, 0, 0, 0)

static constexpr int B_ = 2, S_ = 2048, D_ = 1024, H_ = 16, HD_ = 64;
// Q pre-scale: HD^-0.5 * log2(e)  -> flash softmax in exp2 domain, no max needed
static constexpr float QSCALE = 0.125f * 1.44269504088896340736f;

__device__ __forceinline__ unsigned short f2bf(float f) {
    unsigned int u = __builtin_bit_cast(unsigned int, f);
    u += 0x7fffu + ((u >> 16) & 1);  // round-to-nearest-even
    return (unsigned short)(u >> 16);
}

// packed fp32x2 -> bf16x2 (lo=a, hi=b), RNE. HW inst on gfx950.
#if defined(__has_builtin) && __has_builtin(__builtin_amdgcn_cvt_pk_bf16_f32)
typedef __bf16 bf16x2v __attribute__((ext_vector_type(2)));
__device__ __forceinline__ unsigned int pk_bf16(float a, float b) {
    return __builtin_bit_cast(unsigned int, __builtin_amdgcn_cvt_pk_bf16_f32(a, b));
}
#else
__device__ __forceinline__ unsigned int pk_bf16(float a, float b) {
    return ((unsigned int)f2bf(a)) | (((unsigned int)f2bf(b)) << 16);
}
#endif

__device__ __forceinline__ void glds16(const unsigned short* g, unsigned short* l) {
    __builtin_amdgcn_global_load_lds(
        (const __attribute__((address_space(1))) void*)g,
        (__attribute__((address_space(3))) void*)l, 16, 0, 0);
}

__device__ __forceinline__ void glds16f(const float* g, float* l) {
    __builtin_amdgcn_global_load_lds(
        (const __attribute__((address_space(1))) void*)g,
        (__attribute__((address_space(3))) void*)l, 16, 0, 0);
}

// ---------------------------------------------------------------------------
// Weight transpose: Wt[(h*64+e)*1024 + d] = W[h*65536 + d*64 + e]
// ---------------------------------------------------------------------------
__global__ __launch_bounds__(256) void transpose_w3(const float* __restrict__ W0,
                                                    const float* __restrict__ W1,
                                                    const float* __restrict__ W2,
                                                    unsigned short* __restrict__ Wt3) {
    const int z = blockIdx.z;
    const float* W = (z == 0) ? W0 : (z == 1) ? W1 : W2;
    unsigned short* dst = Wt3 + ((size_t)z << 20);
    const int h = blockIdx.x >> 2, dg = blockIdx.x & 3;
    const int lane = threadIdx.x & 63, w = threadIdx.x >> 6;
    const float* Wh = W + ((size_t)h << 16);
#pragma unroll
    for (int it = 0; it < 8; it++) {
        int d0 = dg * 256 + it * 32 + w * 8;
        us16x8 o;
#pragma unroll
        for (int j = 0; j < 8; j++) o[j] = f2bf(Wh[(d0 + j) * 64 + lane]);
        *(us16x8*)&dst[(size_t)(h * 64 + lane) * 1024 + d0] = o;
    }
}

// ---------------------------------------------------------------------------
// QKV projection GEMM (proven R4 version): A staged directly from f32 inputs.
// A-tile: [128 rows][64 k] f32 in LDS (32 KB), 16-granule/row XOR swizzle;
// bf16 fragments built in-register via cvt_pk (RNE).
// B-tile: bf16 weights (transpose_w3 output), 8-granule swizzle.
// z=0 Q -> row-major [B,S,D] (pre-scaled), z=1 K -> row-major,
// z=2 V -> transposed [B,H,HD,S]. XCD-chunked bijective swizzle (T1).
// ---------------------------------------------------------------------------
__global__ __launch_bounds__(256) void gemm_qkv(const float* __restrict__ Qf,
                                                const float* __restrict__ Kf,
                                                const float* __restrict__ Vf,
                                                const unsigned short* __restrict__ Wt3,
                                                const float* __restrict__ bq,
                                                const float* __restrict__ bk,
                                                const float* __restrict__ bv,
                                                unsigned short* __restrict__ Qr,
                                                unsigned short* __restrict__ Kr,
                                                unsigned short* __restrict__ Vt) {
    __shared__ float Asf[128 * 64];           // 32 KB (f32 A tile)
    __shared__ unsigned short Bs[128 * 64];   // 16 KB (bf16 B tile)
    // flat hw id (x fastest) -> XCD-chunked work id
    const int flat = blockIdx.x + (blockIdx.y << 3) + (blockIdx.z << 8);  // 0..767
    const int wid = (flat & 7) * 96 + (flat >> 3);                        // bijective (768%8==0)
    const int z = wid >> 8;
    const int by = (wid & 255) >> 3;
    const int bx = wid & 7;
    const float* A = (z == 0) ? Qf : (z == 1) ? Kf : Vf;
    const float* bias = (z == 0) ? bq : (z == 1) ? bk : bv;
    const int m0 = by * 128, n0 = bx * 128;

    const int tid = threadIdx.x;
    const int lane = tid & 63;
    const int w = tid >> 6, wm = w & 1, wn = w >> 1;
    const int l16 = lane & 15, quad = lane >> 4;
    // A staging: 16 rows/round, granule su = (tid&15) ^ (row&15)
    const int arow = tid >> 4;
    const int su = (tid & 15) ^ arow;
    const float* Ag = A + (size_t)(m0 + arow) * 1024 + su * 4;
    float* Alf = Asf + tid * 4;
    // B staging: 32 rows/round
    const int srow = tid >> 3;
    const int sg = (tid & 7) ^ (srow & 7);
    const unsigned short* Bg = Wt3 + ((size_t)z << 20) + (size_t)(n0 + srow) * 1024 + sg * 8;
    unsigned short* Bl = Bs + tid * 8;
    const int xo8 = l16 & 7;

    f32x4 acc[4][4] = {};
    for (int k0 = 0; k0 < 1024; k0 += 64) {
        __syncthreads();
#pragma unroll
        for (int c = 0; c < 8; c++)
            glds16f(Ag + (size_t)c * 16 * 1024 + k0, Alf + c * 1024);
#pragma unroll
        for (int c = 0; c < 4; c++)
            glds16(Bg + (size_t)c * 32 * 1024 + k0, Bl + c * 2048);
        __syncthreads();
#pragma unroll
        for (int kc = 0; kc < 2; kc++) {
            s16x8 bf[4];
#pragma unroll
            for (int nt = 0; nt < 4; nt++)
                bf[nt] = *(const s16x8*)&Bs[(wn * 64 + nt * 16 + l16) * 64 +
                                            (((kc * 4 + quad) ^ xo8) * 8)];
#pragma unroll
            for (int mt = 0; mt < 4; mt++) {
                const int row = wm * 64 + mt * 16 + l16;
                const int u = kc * 8 + quad * 2;
                const int e = row & 15;
                f32x4 lo = *(const f32x4*)&Asf[row * 64 + ((u ^ e) * 4)];
                f32x4 hi = *(const f32x4*)&Asf[row * 64 + (((u + 1) ^ e) * 4)];
                s16x8 af;
                ((unsigned int*)&af)[0] = pk_bf16(lo[0], lo[1]);
                ((unsigned int*)&af)[1] = pk_bf16(lo[2], lo[3]);
                ((unsigned int*)&af)[2] = pk_bf16(hi[0], hi[1]);
                ((unsigned int*)&af)[3] = pk_bf16(hi[2], hi[3]);
#pragma unroll
                for (int nt = 0; nt < 4; nt++)
                    acc[mt][nt] = MFMA16(af, bf[nt], acc[mt][nt]);
            }
        }
    }

    const float scl = (z == 0) ? QSCALE : 1.0f;

    __syncthreads();  // all waves done with K-loop LDS reads
    unsigned short* T = ((unsigned short*)Asf) + w * 4096;  // per-wave 64x64 in Asf
#pragma unroll
    for (int mt = 0; mt < 4; mt++)
#pragma unroll
        for (int nt = 0; nt < 4; nt++) {
            int nl = nt * 16 + l16;
            float bsv = bias[n0 + wn * 64 + nl];
#pragma unroll
            for (int r = 0; r < 4; r++) {
                int ml = mt * 16 + quad * 4 + r;
                unsigned short val = f2bf((acc[mt][nt][r] + bsv) * scl);
                int row = (z == 2) ? nl : ml;
                int col = (z == 2) ? ml : nl;
                T[row * 64 + (((col >> 3) ^ (row & 7)) * 8) + (col & 7)] = val;
            }
        }
    // same-wave RAW: compiler orders via lgkmcnt; per-wave private region
#pragma unroll
    for (int it = 0; it < 8; it++) {
        int rr = it * 8 + (lane >> 3);
        int g = lane & 7;
        us16x8 vv = *(const us16x8*)&T[rr * 64 + ((g ^ (rr & 7)) * 8)];
        if (z == 2) {
            int n = n0 + wn * 64 + rr;           // h*64+e
            int mb = m0 + wm * 64 + g * 8;
            int b = mb >> 11, s = mb & 2047;
            *(us16x8*)&Vt[(((size_t)(b * H_ + (n >> 6))) * HD_ + (n & 63)) * S_ + s] = vv;
        } else {
            unsigned short* dst = z ? Kr : Qr;
            *(us16x8*)&dst[(size_t)(m0 + wm * 64 + rr) * 1024 + n0 + wn * 64 + g * 8] = vv;
        }
    }
}

// ---------------------------------------------------------------------------
// Final GEMM v4: C_f32[4096][1024] = Cc * Wp^T + bp.  128x64 tile, 512 blocks
// (2 blocks/CU), BK=128: halves the barrier/drain count (8 K-steps vs 16),
// doubles MFMA per step. Single-buffered 64 KB LDS (same 2-block residency).
//  A (Cc bf16): [128][128] tile, 16-granule XOR (granule=8 shorts, xo=row&15).
//  B (Wp f32):  [64][128] tile, 32 granules of 4 floats, XOR over row&7
//  (rows advance by 8 per staging round so the pattern is round-invariant);
//  bf16 B fragments built in-register via cvt_pk. XCD-chunked swizzle.
// ---------------------------------------------------------------------------
__global__ __launch_bounds__(256) void gemm_out(const unsigned short* __restrict__ A,
                                                const float* __restrict__ Wp,
                                                const float* __restrict__ bias,
                                                float* __restrict__ C) {
    __shared__ unsigned short As[128 * 128];  // 32 KB (bf16 A tile, BK=128)
    __shared__ float Bsf[64 * 128];           // 32 KB (f32 B tile)
    const int tid = threadIdx.x;
    const int lane = tid & 63;
    const int w = tid >> 6, wm = w & 1, wn = w >> 1;  // wn 0..1
    const int l16 = lane & 15, quad = lane >> 4;
    const int flat = blockIdx.x + (blockIdx.y << 4);  // 0..511
    const int wid = (flat & 7) * 64 + (flat >> 3);    // bijective (512%8==0)
    const int m0 = (wid >> 4) * 128, n0 = (wid & 15) * 64;
    // A staging: 16 rows/round (tid>>4 = row-in-round, tid&15 = granule slot)
    const int arow = tid >> 4;                 // 0..15 (= tile-row & 15 every round)
    const int ag = (tid & 15) ^ arow;          // inverse-swizzled source granule
    const unsigned short* Ag = A + (size_t)(m0 + arow) * 1024 + ag * 8;
    unsigned short* Al = As + tid * 8;
    // B staging: 8 rows/round (tid>>5 = row-in-round, tid&31 = granule of 4 floats)
    const int brow = tid >> 5;                 // 0..7 (= tile-row & 7 every round)
    const int bg = (tid & 31) ^ brow;          // XOR low-3 bits, bijective in 0..31
    const float* Bg = Wp + (size_t)(n0 + brow) * 1024 + bg * 4;
    float* Blf = Bsf + tid * 4;

    f32x4 acc[4][2] = {};
    for (int k0 = 0; k0 < 1024; k0 += 128) {
        __syncthreads();
#pragma unroll
        for (int c = 0; c < 8; c++)
            glds16(Ag + (size_t)c * 16 * 1024 + k0, Al + c * 2048);
#pragma unroll
        for (int c = 0; c < 8; c++)
            glds16f(Bg + (size_t)c * 8 * 1024 + k0, Blf + c * 1024);
        __syncthreads();
#pragma unroll
        for (int kc = 0; kc < 4; kc++) {
            s16x8 bf[2];
#pragma unroll
            for (int nt = 0; nt < 2; nt++) {
                const int row = wn * 32 + nt * 16 + l16;
                const int u = kc * 8 + quad * 2;
                const int e7 = row & 7;
                f32x4 lo = *(const f32x4*)&Bsf[row * 128 + ((u ^ e7) * 4)];
                f32x4 hi = *(const f32x4*)&Bsf[row * 128 + (((u + 1) ^ e7) * 4)];
                ((unsigned int*)&bf[nt])[0] = pk_bf16(lo[0], lo[1]);
                ((unsigned int*)&bf[nt])[1] = pk_bf16(lo[2], lo[3]);
                ((unsigned int*)&bf[nt])[2] = pk_bf16(hi[0], hi[1]);
                ((unsigned int*)&bf[nt])[3] = pk_bf16(hi[2], hi[3]);
            }
#pragma unroll
            for (int mt = 0; mt < 4; mt++) {
                const int row = wm * 64 + mt * 16 + l16;
                s16x8 af = *(const s16x8*)&As[row * 128 +
                                              (((kc * 4 + quad) ^ (row & 15)) * 8)];
#pragma unroll
                for (int nt = 0; nt < 2; nt++)
                    acc[mt][nt] = MFMA16(af, bf[nt], acc[mt][nt]);
            }
        }
    }
    const int lq = quad;
#pragma unroll
    for (int mt = 0; mt < 4; mt++)
#pragma unroll
        for (int nt = 0; nt < 2; nt++)
#pragma unroll
            for (int r = 0; r < 4; r++) {
                int mg = m0 + wm * 64 + mt * 16 + lq * 4 + r;
                int ng = n0 + wn * 32 + nt * 16 + l16;
                C[(size_t)mg * 1024 + ng] = acc[mt][nt][r] + bias[ng];
            }
}

// ---------------------------------------------------------------------------
// Flash attention v6 (best measured): pipelined staging.
//  K double-buffered + 1-iter-ahead prefetch; V single-buffered with counted
//  vmcnt(2) mid-barrier (K prefetch stays in flight); s_setprio around MFMA.
// Q,K row-major [B,S,D] bf16 (Q pre-scaled); V: [B,H,HD,S].
// grid: x = bh (all q-blocks of a head land on one XCD), y = q-block.
// ---------------------------------------------------------------------------
__global__ __launch_bounds__(256) void flash_attn(const unsigned short* __restrict__ Qr,
                                                  const unsigned short* __restrict__ Kr,
                                                  const unsigned short* __restrict__ Vt,
                                                  unsigned short* __restrict__ Cc) {
    __shared__ unsigned short Ks[2][64 * 64];    // [buf][key][d], double-buffered
    __shared__ unsigned short Vs[64 * 64];       // [e][s-rel], single-buffered
    constexpr int LDT = 72;
    __shared__ unsigned short P4[4][16 * LDT];   // per-wave P^T: [q][key]

    const int tid = threadIdx.x;
    const int lane = tid & 63, w = tid >> 6;
    const int l16 = lane & 15, quad = lane >> 4;
    const int bh = blockIdx.x, q0 = blockIdx.y * 64;
    const int b = bh >> 4, h = bh & 15;
    const int s_q = q0 + w * 16 + l16;           // this lane's q-row

    const unsigned short* Qp = Qr + ((size_t)(b * S_ + s_q)) * D_ + h * HD_;

    const int srow = tid >> 3;
    const int sg = (tid & 7) ^ (srow & 7);
    const unsigned short* kg = Kr + ((size_t)(b * S_ + srow)) * D_ + h * HD_ + sg * 8;
    const unsigned short* vg = Vt + (((size_t)(b * H_ + h)) * HD_ + srow) * S_ + sg * 8;
    unsigned short* Vl = Vs + tid * 8;
    unsigned short* Pw = P4[w];
    const int pbase = l16 * LDT + quad * 4;      // P store base (per-lane)
    const int xo = l16 & 7;

    // prologue: stage K tile 0 into Ks[0]
    glds16(kg, &Ks[0][tid * 8]);
    glds16(kg + (size_t)32 * D_, &Ks[0][tid * 8 + 2048]);
    kg += (size_t)64 * D_;

    s16x8 aq0 = *(const s16x8*)&Qp[quad * 8];
    s16x8 aq1 = *(const s16x8*)&Qp[32 + quad * 8];

    float l_part = 0.f;
    f32x4 o[4] = {};
    const f32x4 z4 = {0.f, 0.f, 0.f, 0.f};

    asm volatile("s_waitcnt vmcnt(0) lgkmcnt(0)\n\ts_barrier" ::: "memory");

    int cur = 0;
    for (int t = 0; t < 32; ++t) {
        const int last = (t == 31);
        // stage V(t): Vs free (all waves finished PV(t-1) before last barrier)
        glds16(vg, Vl);
        glds16(vg + (size_t)32 * S_, Vl + 2048);
        vg += 64;
        if (!last) {
            // stage K(t+1) into the other K buffer (read slot freed at iter t-1)
            unsigned short* Kn = &Ks[cur ^ 1][tid * 8];
            glds16(kg, Kn);
            glds16(kg + (size_t)32 * D_, Kn + 2048);
            kg += (size_t)64 * D_;
        }

        // scores^T on Ks[cur]: D[key][q] = K·Q^T ; keys g*16+quad*4+r, col q=l16
        const unsigned short* Kc_ = &Ks[cur][0];
        __builtin_amdgcn_s_setprio(1);
#pragma unroll
        for (int g = 0; g < 4; g++) {
            int row = g * 16 + l16;
            s16x8 kb0 = *(const s16x8*)&Kc_[row * 64 + ((quad ^ xo) * 8)];
            s16x8 kb1 = *(const s16x8*)&Kc_[row * 64 + (((4 + quad) ^ xo) * 8)];
            f32x4 sc = MFMA16(kb0, aq0, z4);
            sc = MFMA16(kb1, aq1, sc);
            float e0 = exp2f(sc[0]), e1 = exp2f(sc[1]);
            float e2 = exp2f(sc[2]), e3 = exp2f(sc[3]);
            l_part += (e0 + e1) + (e2 + e3);
            u32x2 pv;
            pv[0] = pk_bf16(e0, e1);
            pv[1] = pk_bf16(e2, e3);
            *(u32x2*)&Pw[pbase + g * 16] = pv;   // 4 contig keys, 8B store
        }
        __builtin_amdgcn_s_setprio(0);
        // P as B-operand for PV: B[k=key][n=q] = Pw[q=l16][key] (same-wave, DS in-order)
        s16x8 pB0 = *(const s16x8*)&Pw[l16 * LDT + quad * 8];
        s16x8 pB1 = *(const s16x8*)&Pw[l16 * LDT + 32 + quad * 8];

        // mid-iter: V(t) landed (leave the 2 newer K(t+1) glds in flight), all waves sync
        if (!last)
            asm volatile("s_waitcnt vmcnt(2)\n\ts_barrier" ::: "memory");
        else
            asm volatile("s_waitcnt vmcnt(0)\n\ts_barrier" ::: "memory");

        // o^T[e][q] += V^T · P^T
        __builtin_amdgcn_s_setprio(1);
#pragma unroll
        for (int tt = 0; tt < 4; tt++) {
            int row = tt * 16 + l16;
            s16x8 v0 = *(const s16x8*)&Vs[row * 64 + ((quad ^ xo) * 8)];
            s16x8 v1 = *(const s16x8*)&Vs[row * 64 + (((4 + quad) ^ xo) * 8)];
            o[tt] = MFMA16(v0, pB0, o[tt]);
            o[tt] = MFMA16(v1, pB1, o[tt]);
        }
        __builtin_amdgcn_s_setprio(0);
        // end-of-iter: my LDS reads retired (Ks[cur]/Vs safe to overwrite next iter),
        // K(t+1) landed (had a full iteration of slack)
        asm volatile("s_waitcnt vmcnt(0) lgkmcnt(0)\n\ts_barrier" ::: "memory");
        cur ^= 1;
    }

    float l = l_part;
    l += __shfl_xor(l, 16);
    l += __shfl_xor(l, 32);
    float rinv = 1.0f / l;
    unsigned short* Cp = Cc + ((size_t)(b * S_ + s_q)) * D_ + h * HD_;
#pragma unroll
    for (int t = 0; t < 4; t++) {
        u32x2 ov;
        ov[0] = pk_bf16(o[t][0] * rinv, o[t][1] * rinv);
        ov[1] = pk_bf16(o[t][2] * rinv, o[t][3] * rinv);
        *(u32x2*)&Cp[t * 16 + quad * 4] = ov;
    }
}

// ---------------------------------------------------------------------------
extern "C" void kernel_launch(void* const* d_in, const int* in_sizes, int n_in,
                              void* d_out, int out_size, void* d_ws, size_t ws_size,
                              hipStream_t stream) {
    const float* K_in = (const float*)d_in[0];
    const float* V_in = (const float*)d_in[1];
    const float* Q_in = (const float*)d_in[2];
    const float* Wk   = (const float*)d_in[3];
    const float* bk   = (const float*)d_in[4];
    const float* Wq   = (const float*)d_in[5];
    const float* bq   = (const float*)d_in[6];
    const float* Wv   = (const float*)d_in[7];
    const float* bv   = (const float*)d_in[8];
    const float* Wp   = (const float*)d_in[9];
    const float* bp   = (const float*)d_in[10];

    unsigned short* ws16 = (unsigned short*)d_ws;
    const size_t MC = 1u << 20;
    unsigned short* Wt3 = ws16;            // 3M bf16 transposed QKV weights
    unsigned short* Qr  = Wt3 + 3 * MC;    // 4M [B,S,D] projected, pre-scaled
    unsigned short* Kr  = Qr + 4 * MC;     // 4M [B,S,D]
    unsigned short* Vt  = Kr + 4 * MC;     // 4M [B,H,HD,S]
    unsigned short* Cc  = Vt + 4 * MC;     // 4M [B,S,D] attention output

    transpose_w3<<<dim3(64, 1, 3), 256, 0, stream>>>(Wq, Wk, Wv, Wt3);

    gemm_qkv<<<dim3(8, 32, 3), 256, 0, stream>>>(Q_in, K_in, V_in, Wt3, bq, bk, bv,
                                                 Qr, Kr, Vt);

    flash_attn<<<dim3(32, 32), 256, 0, stream>>>(Qr, Kr, Vt, Cc);

    gemm_out<<<dim3(16, 32), 256, 0, stream>>>(Cc, Wp, bp, (float*)d_out);
}

// Round 8
// 251.345 us; speedup vs baseline: 1.1558x; 1.0017x over previous
//
#include <hip/hip_runtime.h>
#include <hip/hip_bf16.h>
#include <math.h>

typedef float f32x4 __attribute__((ext_vector_type(4)));
typedef short s16x8 __attribute__((ext_vector_type(8)));
typedef unsigned short us16x4 __attribute__((ext_vector_type(4)));
typedef unsigned short us16x8 __attribute__((ext_vector_type(8)));
typedef unsigned int u32x2 __attribute__((ext_vector_type(2)));

#define MFMA16(a, b, c) __builtin_amdgcn_mfma_f32_16x16x32_bf16(a, b, c, 0, 0, 0)

static constexpr int B_ = 2, S_ = 2048, D_ = 1024, H_ = 16, HD_ = 64;
// Q pre-scale: HD^-0.5 * log2(e)  -> flash softmax in exp2 domain, no max needed
static constexpr float QSCALE = 0.125f * 1.44269504088896340736f;

__device__ __forceinline__ unsigned short f2bf(float f) {
    unsigned int u = __builtin_bit_cast(unsigned int, f);
    u += 0x7fffu + ((u >> 16) & 1);  // round-to-nearest-even
    return (unsigned short)(u >> 16);
}

// packed fp32x2 -> bf16x2 (lo=a, hi=b), RNE. HW inst on gfx950.
#if defined(__has_builtin) && __has_builtin(__builtin_amdgcn_cvt_pk_bf16_f32)
typedef __bf16 bf16x2v __attribute__((ext_vector_type(2)));
__device__ __forceinline__ unsigned int pk_bf16(float a, float b) {
    return __builtin_bit_cast(unsigned int, __builtin_amdgcn_cvt_pk_bf16_f32(a, b));
}
#else
__device__ __forceinline__ unsigned int pk_bf16(float a, float b) {
    return ((unsigned int)f2bf(a)) | (((unsigned int)f2bf(b)) << 16);
}
#endif

__device__ __forceinline__ void glds16(const unsigned short* g, unsigned short* l) {
    __builtin_amdgcn_global_load_lds(
        (const __attribute__((address_space(1))) void*)g,
        (__attribute__((address_space(3))) void*)l, 16, 0, 0);
}

// ---------------------------------------------------------------------------
// fp32 -> bf16 flat converts (proven R0-R3)
// ---------------------------------------------------------------------------
__global__ __launch_bounds__(256) void conv3(const float* __restrict__ s0,
                                             const float* __restrict__ s1,
                                             const float* __restrict__ s2,
                                             unsigned short* __restrict__ d0,
                                             unsigned short* __restrict__ d1,
                                             unsigned short* __restrict__ d2) {
    const int z = blockIdx.z;
    const float* src = (z == 0) ? s0 : (z == 1) ? s1 : s2;
    unsigned short* dst = (z == 0) ? d0 : (z == 1) ? d1 : d2;
    int i = (blockIdx.x * 256 + threadIdx.x) * 8;
    f32x4 a = *(const f32x4*)&src[i];
    f32x4 b = *(const f32x4*)&src[i + 4];
    s16x8 o;
#pragma unroll
    for (int j = 0; j < 4; j++) { o[j] = (short)f2bf(a[j]); o[4 + j] = (short)f2bf(b[j]); }
    *(s16x8*)&dst[i] = o;
}

__global__ __launch_bounds__(256) void conv_bf16(const float* __restrict__ src,
                                                 unsigned short* __restrict__ dst) {
    int i = (blockIdx.x * 256 + threadIdx.x) * 8;
    f32x4 a = *(const f32x4*)&src[i];
    f32x4 b = *(const f32x4*)&src[i + 4];
    s16x8 o;
#pragma unroll
    for (int j = 0; j < 4; j++) { o[j] = (short)f2bf(a[j]); o[4 + j] = (short)f2bf(b[j]); }
    *(s16x8*)&dst[i] = o;
}

// ---------------------------------------------------------------------------
// Weight transpose: Wt[(h*64+e)*1024 + d] = W[h*65536 + d*64 + e]
// ---------------------------------------------------------------------------
__global__ __launch_bounds__(256) void transpose_w3(const float* __restrict__ W0,
                                                    const float* __restrict__ W1,
                                                    const float* __restrict__ W2,
                                                    unsigned short* __restrict__ Wt3) {
    const int z = blockIdx.z;
    const float* W = (z == 0) ? W0 : (z == 1) ? W1 : W2;
    unsigned short* dst = Wt3 + ((size_t)z << 20);
    const int h = blockIdx.x >> 2, dg = blockIdx.x & 3;
    const int lane = threadIdx.x & 63, w = threadIdx.x >> 6;
    const float* Wh = W + ((size_t)h << 16);
#pragma unroll
    for (int it = 0; it < 8; it++) {
        int d0 = dg * 256 + it * 32 + w * 8;
        us16x8 o;
#pragma unroll
        for (int j = 0; j < 8; j++) o[j] = f2bf(Wh[(d0 + j) * 64 + lane]);
        *(us16x8*)&dst[(size_t)(h * 64 + lane) * 1024 + d0] = o;
    }
}

// ---------------------------------------------------------------------------
// QKV projection GEMM v5: 2-phase issue-early/single-barrier (T3-minimum).
//  Double-buffered bf16 A/B tiles via global_load_lds only (64 KB, 2 blk/CU).
//  Per K-step: issue 8 glds for tile t+1 into buf^1 FIRST, then ds_read+MFMA
//  tile t, then ONE vmcnt(0)+barrier — glds latency hides under ~700 cy of
//  compute instead of being drained immediately (the old 2-barrier pattern).
//  Inner loop, swizzle, epilogue: byte-identical to the R0-proven kernel.
// z=0 Q (pre-scaled), z=1 K, z=2 V -> [B,H,HD,S]. XCD-chunked swizzle (T1).
// ---------------------------------------------------------------------------
__global__ __launch_bounds__(256) void gemm_qkv(const unsigned short* __restrict__ Qc,
                                                const unsigned short* __restrict__ Kc,
                                                const unsigned short* __restrict__ Vc,
                                                const unsigned short* __restrict__ Wt3,
                                                const float* __restrict__ bq,
                                                const float* __restrict__ bk,
                                                const float* __restrict__ bv,
                                                unsigned short* __restrict__ Qr,
                                                unsigned short* __restrict__ Kr,
                                                unsigned short* __restrict__ Vt) {
    __shared__ unsigned short As[2][128 * 64];   // 2 x 16 KB
    __shared__ unsigned short Bs[2][128 * 64];   // 2 x 16 KB
    const int flat = blockIdx.x + (blockIdx.y << 3) + (blockIdx.z << 8);  // 0..767
    const int wid = (flat & 7) * 96 + (flat >> 3);                        // bijective
    const int z = wid >> 8;
    const int by = (wid & 255) >> 3;
    const int bx = wid & 7;
    const unsigned short* A = (z == 0) ? Qc : (z == 1) ? Kc : Vc;
    const unsigned short* Bt = Wt3 + ((size_t)z << 20);
    const float* bias = (z == 0) ? bq : (z == 1) ? bk : bv;
    const int m0 = by * 128, n0 = bx * 128;

    const int tid = threadIdx.x;
    const int lane = tid & 63;
    const int w = tid >> 6, wm = w & 1, wn = w >> 1;
    const int l16 = lane & 15, quad = lane >> 4;
    const int srow = tid >> 3;
    const int sg = (tid & 7) ^ (srow & 7);
    const unsigned short* Ag = A + (size_t)(m0 + srow) * 1024 + sg * 8;
    const unsigned short* Bg = Bt + (size_t)(n0 + srow) * 1024 + sg * 8;
    const int xo = l16 & 7;

    f32x4 acc[4][4] = {};

    // prologue: stage tile 0 into buf 0, full drain once
#pragma unroll
    for (int c = 0; c < 4; c++) {
        glds16(Ag + (size_t)c * 32 * 1024, &As[0][tid * 8 + c * 2048]);
        glds16(Bg + (size_t)c * 32 * 1024, &Bs[0][tid * 8 + c * 2048]);
    }
    asm volatile("s_waitcnt vmcnt(0)\n\ts_barrier" ::: "memory");

    int cur = 0;
    for (int t = 0; t < 16; ++t) {
        if (t < 15) {
            // issue-early: stage tile t+1 into the other buffer BEFORE compute
            const int k0n = (t + 1) * 64;
#pragma unroll
            for (int c = 0; c < 4; c++) {
                glds16(Ag + (size_t)c * 32 * 1024 + k0n, &As[cur ^ 1][tid * 8 + c * 2048]);
                glds16(Bg + (size_t)c * 32 * 1024 + k0n, &Bs[cur ^ 1][tid * 8 + c * 2048]);
            }
        }
        // compute tile t (R0-proven inner loop)
        const unsigned short* Ac = &As[cur][0];
        const unsigned short* Bc = &Bs[cur][0];
        __builtin_amdgcn_s_setprio(1);
#pragma unroll
        for (int kc = 0; kc < 2; kc++) {
            s16x8 bf[4];
#pragma unroll
            for (int nt = 0; nt < 4; nt++)
                bf[nt] = *(const s16x8*)&Bc[(wn * 64 + nt * 16 + l16) * 64 +
                                            (((kc * 4 + quad) ^ xo) * 8)];
#pragma unroll
            for (int mt = 0; mt < 4; mt++) {
                s16x8 af = *(const s16x8*)&Ac[(wm * 64 + mt * 16 + l16) * 64 +
                                              (((kc * 4 + quad) ^ xo) * 8)];
#pragma unroll
                for (int nt = 0; nt < 4; nt++)
                    acc[mt][nt] = MFMA16(af, bf[nt], acc[mt][nt]);
            }
        }
        __builtin_amdgcn_s_setprio(0);
        // single barrier per step: t+1 glds landed (hidden under compute);
        // all waves' ds_reads of buf cur were consumed before this point.
        asm volatile("s_waitcnt vmcnt(0)\n\ts_barrier" ::: "memory");
        cur ^= 1;
    }

    const float scl = (z == 0) ? QSCALE : 1.0f;

    __syncthreads();  // all waves done with K-loop LDS reads
    unsigned short* T = ((unsigned short*)As) + w * 4096;  // per-wave 64x64 (32 KB of As)
#pragma unroll
    for (int mt = 0; mt < 4; mt++)
#pragma unroll
        for (int nt = 0; nt < 4; nt++) {
            int nl = nt * 16 + l16;
            float bsv = bias[n0 + wn * 64 + nl];
#pragma unroll
            for (int r = 0; r < 4; r++) {
                int ml = mt * 16 + quad * 4 + r;
                unsigned short val = f2bf((acc[mt][nt][r] + bsv) * scl);
                int row = (z == 2) ? nl : ml;
                int col = (z == 2) ? ml : nl;
                T[row * 64 + (((col >> 3) ^ (row & 7)) * 8) + (col & 7)] = val;
            }
        }
    // same-wave RAW: compiler orders via lgkmcnt; per-wave private region
#pragma unroll
    for (int it = 0; it < 8; it++) {
        int rr = it * 8 + (lane >> 3);
        int g = lane & 7;
        us16x8 vv = *(const us16x8*)&T[rr * 64 + ((g ^ (rr & 7)) * 8)];
        if (z == 2) {
            int n = n0 + wn * 64 + rr;           // h*64+e
            int mb = m0 + wm * 64 + g * 8;
            int b = mb >> 11, s = mb & 2047;
            *(us16x8*)&Vt[(((size_t)(b * H_ + (n >> 6))) * HD_ + (n & 63)) * S_ + s] = vv;
        } else {
            unsigned short* dst = z ? Kr : Qr;
            *(us16x8*)&dst[(size_t)(m0 + wm * 64 + rr) * 1024 + n0 + wn * 64 + g * 8] = vv;
        }
    }
}

// ---------------------------------------------------------------------------
// Final GEMM v5: C_f32[4096][1024] = Cc * Wp^T + bp.  128x64 tile, 512 blocks.
// Same 2-phase issue-early/single-barrier schedule; bf16 A (Cc) and bf16 B
// (conv_bf16'd Wp), dbuf 48 KB. Inner loop/epilogue = R0-proven. XCD swizzle.
// ---------------------------------------------------------------------------
__global__ __launch_bounds__(256) void gemm_out(const unsigned short* __restrict__ A,
                                                const unsigned short* __restrict__ Bt,
                                                const float* __restrict__ bias,
                                                float* __restrict__ C) {
    __shared__ unsigned short As[2][128 * 64];   // 2 x 16 KB
    __shared__ unsigned short Bs[2][64 * 64];    // 2 x 8 KB
    const int tid = threadIdx.x;
    const int lane = tid & 63;
    const int w = tid >> 6, wm = w & 1, wn = w >> 1;  // wn 0..1
    const int l16 = lane & 15, quad = lane >> 4;
    const int flat = blockIdx.x + (blockIdx.y << 4);  // 0..511
    const int wid = (flat & 7) * 64 + (flat >> 3);    // bijective (512%8==0)
    const int m0 = (wid >> 4) * 128, n0 = (wid & 15) * 64;
    const int srow = tid >> 3;
    const int sg = (tid & 7) ^ (srow & 7);
    const unsigned short* Ag = A + (size_t)(m0 + srow) * 1024 + sg * 8;
    const unsigned short* Bg = Bt + (size_t)(n0 + srow) * 1024 + sg * 8;
    const int xo = l16 & 7;

    f32x4 acc[4][2] = {};

    // prologue: stage tile 0
#pragma unroll
    for (int c = 0; c < 4; c++)
        glds16(Ag + (size_t)c * 32 * 1024, &As[0][tid * 8 + c * 2048]);
#pragma unroll
    for (int c = 0; c < 2; c++)
        glds16(Bg + (size_t)c * 32 * 1024, &Bs[0][tid * 8 + c * 2048]);
    asm volatile("s_waitcnt vmcnt(0)\n\ts_barrier" ::: "memory");

    int cur = 0;
    for (int t = 0; t < 16; ++t) {
        if (t < 15) {
            const int k0n = (t + 1) * 64;
#pragma unroll
            for (int c = 0; c < 4; c++)
                glds16(Ag + (size_t)c * 32 * 1024 + k0n, &As[cur ^ 1][tid * 8 + c * 2048]);
#pragma unroll
            for (int c = 0; c < 2; c++)
                glds16(Bg + (size_t)c * 32 * 1024 + k0n, &Bs[cur ^ 1][tid * 8 + c * 2048]);
        }
        const unsigned short* Ac = &As[cur][0];
        const unsigned short* Bc = &Bs[cur][0];
        __builtin_amdgcn_s_setprio(1);
#pragma unroll
        for (int kc = 0; kc < 2; kc++) {
            s16x8 bf[2];
#pragma unroll
            for (int nt = 0; nt < 2; nt++)
                bf[nt] = *(const s16x8*)&Bc[(wn * 32 + nt * 16 + l16) * 64 +
                                            (((kc * 4 + quad) ^ xo) * 8)];
#pragma unroll
            for (int mt = 0; mt < 4; mt++) {
                s16x8 af = *(const s16x8*)&Ac[(wm * 64 + mt * 16 + l16) * 64 +
                                              (((kc * 4 + quad) ^ xo) * 8)];
#pragma unroll
                for (int nt = 0; nt < 2; nt++)
                    acc[mt][nt] = MFMA16(af, bf[nt], acc[mt][nt]);
            }
        }
        __builtin_amdgcn_s_setprio(0);
        asm volatile("s_waitcnt vmcnt(0)\n\ts_barrier" ::: "memory");
        cur ^= 1;
    }
    const int lq = quad;
#pragma unroll
    for (int mt = 0; mt < 4; mt++)
#pragma unroll
        for (int nt = 0; nt < 2; nt++)
#pragma unroll
            for (int r = 0; r < 4; r++) {
                int mg = m0 + wm * 64 + mt * 16 + lq * 4 + r;
                int ng = n0 + wn * 32 + nt * 16 + l16;
                C[(size_t)mg * 1024 + ng] = acc[mt][nt][r] + bias[ng];
            }
}

// ---------------------------------------------------------------------------
// Flash attention v6 (best measured): pipelined staging.
//  K double-buffered + 1-iter-ahead prefetch; V single-buffered with counted
//  vmcnt(2) mid-barrier (K prefetch stays in flight); s_setprio around MFMA.
// Q,K row-major [B,S,D] bf16 (Q pre-scaled); V: [B,H,HD,S].
// grid: x = bh (all q-blocks of a head land on one XCD), y = q-block.
// ---------------------------------------------------------------------------
__global__ __launch_bounds__(256) void flash_attn(const unsigned short* __restrict__ Qr,
                                                  const unsigned short* __restrict__ Kr,
                                                  const unsigned short* __restrict__ Vt,
                                                  unsigned short* __restrict__ Cc) {
    __shared__ unsigned short Ks[2][64 * 64];    // [buf][key][d], double-buffered
    __shared__ unsigned short Vs[64 * 64];       // [e][s-rel], single-buffered
    constexpr int LDT = 72;
    __shared__ unsigned short P4[4][16 * LDT];   // per-wave P^T: [q][key]

    const int tid = threadIdx.x;
    const int lane = tid & 63, w = tid >> 6;
    const int l16 = lane & 15, quad = lane >> 4;
    const int bh = blockIdx.x, q0 = blockIdx.y * 64;
    const int b = bh >> 4, h = bh & 15;
    const int s_q = q0 + w * 16 + l16;           // this lane's q-row

    const unsigned short* Qp = Qr + ((size_t)(b * S_ + s_q)) * D_ + h * HD_;

    const int srow = tid >> 3;
    const int sg = (tid & 7) ^ (srow & 7);
    const unsigned short* kg = Kr + ((size_t)(b * S_ + srow)) * D_ + h * HD_ + sg * 8;
    const unsigned short* vg = Vt + (((size_t)(b * H_ + h)) * HD_ + srow) * S_ + sg * 8;
    unsigned short* Vl = Vs + tid * 8;
    unsigned short* Pw = P4[w];
    const int pbase = l16 * LDT + quad * 4;      // P store base (per-lane)
    const int xo = l16 & 7;

    // prologue: stage K tile 0 into Ks[0]
    glds16(kg, &Ks[0][tid * 8]);
    glds16(kg + (size_t)32 * D_, &Ks[0][tid * 8 + 2048]);
    kg += (size_t)64 * D_;

    s16x8 aq0 = *(const s16x8*)&Qp[quad * 8];
    s16x8 aq1 = *(const s16x8*)&Qp[32 + quad * 8];

    float l_part = 0.f;
    f32x4 o[4] = {};
    const f32x4 z4 = {0.f, 0.f, 0.f, 0.f};

    asm volatile("s_waitcnt vmcnt(0) lgkmcnt(0)\n\ts_barrier" ::: "memory");

    int cur = 0;
    for (int t = 0; t < 32; ++t) {
        const int last = (t == 31);
        // stage V(t): Vs free (all waves finished PV(t-1) before last barrier)
        glds16(vg, Vl);
        glds16(vg + (size_t)32 * S_, Vl + 2048);
        vg += 64;
        if (!last) {
            // stage K(t+1) into the other K buffer (read slot freed at iter t-1)
            unsigned short* Kn = &Ks[cur ^ 1][tid * 8];
            glds16(kg, Kn);
            glds16(kg + (size_t)32 * D_, Kn + 2048);
            kg += (size_t)64 * D_;
        }

        // scores^T on Ks[cur]: D[key][q] = K·Q^T ; keys g*16+quad*4+r, col q=l16
        const unsigned short* Kc_ = &Ks[cur][0];
        __builtin_amdgcn_s_setprio(1);
#pragma unroll
        for (int g = 0; g < 4; g++) {
            int row = g * 16 + l16;
            s16x8 kb0 = *(const s16x8*)&Kc_[row * 64 + ((quad ^ xo) * 8)];
            s16x8 kb1 = *(const s16x8*)&Kc_[row * 64 + (((4 + quad) ^ xo) * 8)];
            f32x4 sc = MFMA16(kb0, aq0, z4);
            sc = MFMA16(kb1, aq1, sc);
            float e0 = exp2f(sc[0]), e1 = exp2f(sc[1]);
            float e2 = exp2f(sc[2]), e3 = exp2f(sc[3]);
            l_part += (e0 + e1) + (e2 + e3);
            u32x2 pv;
            pv[0] = pk_bf16(e0, e1);
            pv[1] = pk_bf16(e2, e3);
            *(u32x2*)&Pw[pbase + g * 16] = pv;   // 4 contig keys, 8B store
        }
        __builtin_amdgcn_s_setprio(0);
        // P as B-operand for PV: B[k=key][n=q] = Pw[q=l16][key] (same-wave, DS in-order)
        s16x8 pB0 = *(const s16x8*)&Pw[l16 * LDT + quad * 8];
        s16x8 pB1 = *(const s16x8*)&Pw[l16 * LDT + 32 + quad * 8];

        // mid-iter: V(t) landed (leave the 2 newer K(t+1) glds in flight), all waves sync
        if (!last)
            asm volatile("s_waitcnt vmcnt(2)\n\ts_barrier" ::: "memory");
        else
            asm volatile("s_waitcnt vmcnt(0)\n\ts_barrier" ::: "memory");

        // o^T[e][q] += V^T · P^T
        __builtin_amdgcn_s_setprio(1);
#pragma unroll
        for (int tt = 0; tt < 4; tt++) {
            int row = tt * 16 + l16;
            s16x8 v0 = *(const s16x8*)&Vs[row * 64 + ((quad ^ xo) * 8)];
            s16x8 v1 = *(const s16x8*)&Vs[row * 64 + (((4 + quad) ^ xo) * 8)];
            o[tt] = MFMA16(v0, pB0, o[tt]);
            o[tt] = MFMA16(v1, pB1, o[tt]);
        }
        __builtin_amdgcn_s_setprio(0);
        // end-of-iter: my LDS reads retired (Ks[cur]/Vs safe to overwrite next iter),
        // K(t+1) landed (had a full iteration of slack)
        asm volatile("s_waitcnt vmcnt(0) lgkmcnt(0)\n\ts_barrier" ::: "memory");
        cur ^= 1;
    }

    float l = l_part;
    l += __shfl_xor(l, 16);
    l += __shfl_xor(l, 32);
    float rinv = 1.0f / l;
    unsigned short* Cp = Cc + ((size_t)(b * S_ + s_q)) * D_ + h * HD_;
#pragma unroll
    for (int t = 0; t < 4; t++) {
        u32x2 ov;
        ov[0] = pk_bf16(o[t][0] * rinv, o[t][1] * rinv);
        ov[1] = pk_bf16(o[t][2] * rinv, o[t][3] * rinv);
        *(u32x2*)&Cp[t * 16 + quad * 4] = ov;
    }
}

// ---------------------------------------------------------------------------
extern "C" void kernel_launch(void* const* d_in, const int* in_sizes, int n_in,
                              void* d_out, int out_size, void* d_ws, size_t ws_size,
                              hipStream_t stream) {
    const float* K_in = (const float*)d_in[0];
    const float* V_in = (const float*)d_in[1];
    const float* Q_in = (const float*)d_in[2];
    const float* Wk   = (const float*)d_in[3];
    const float* bk   = (const float*)d_in[4];
    const float* Wq   = (const float*)d_in[5];
    const float* bq   = (const float*)d_in[6];
    const float* Wv   = (const float*)d_in[7];
    const float* bv   = (const float*)d_in[8];
    const float* Wp   = (const float*)d_in[9];
    const float* bp   = (const float*)d_in[10];

    unsigned short* ws16 = (unsigned short*)d_ws;
    const size_t MC = 1u << 20;
    unsigned short* Qc  = ws16;            // 4M bf16 [B,S,D]
    unsigned short* Kc  = Qc + 4 * MC;
    unsigned short* Vc  = Kc + 4 * MC;
    unsigned short* Wt3 = Vc + 4 * MC;     // 3M
    unsigned short* Qr  = Wt3 + 3 * MC;    // 4M [B,S,D] projected, pre-scaled
    unsigned short* Kr  = Qr + 4 * MC;     // 4M [B,S,D]
    unsigned short* Vt  = Kr + 4 * MC;     // 4M [B,H,HD,S]
    unsigned short* Cc  = Qc;              // alias: Qc dead after gemm_qkv
    unsigned short* Wpb = Wt3;             // alias: Wt3 dead after gemm_qkv

    conv3<<<dim3(2048, 1, 3), 256, 0, stream>>>(Q_in, K_in, V_in, Qc, Kc, Vc);
    transpose_w3<<<dim3(64, 1, 3), 256, 0, stream>>>(Wq, Wk, Wv, Wt3);

    gemm_qkv<<<dim3(8, 32, 3), 256, 0, stream>>>(Qc, Kc, Vc, Wt3, bq, bk, bv, Qr, Kr, Vt);

    conv_bf16<<<512, 256, 0, stream>>>(Wp, Wpb);

    flash_attn<<<dim3(32, 32), 256, 0, stream>>>(Qr, Kr, Vt, Cc);

    gemm_out<<<dim3(16, 32), 256, 0, stream>>>(Cc, Wpb, bp, (float*)d_out);
}